// Round 3
// baseline (230.522 us; speedup 1.0000x reference)
//
#include <hip/hip_runtime.h>

typedef float f32x4 __attribute__((ext_vector_type(4)));

#define DIM 512
#define WPB 4                 // waves per block
#define BLOCK (64 * WPB)      // 256 threads
#define ROWS_PER_BLOCK (WPB * 2)

// ds_swizzle BitMode operates independently within each 32-lane group:
// 5-stage xor butterfly = full 32-lane allreduce, no cross-32 stage needed.
__device__ __forceinline__ float swz_add(float x) {
    x += __int_as_float(__builtin_amdgcn_ds_swizzle(__float_as_int(x), (1  << 10) | 0x1f));
    x += __int_as_float(__builtin_amdgcn_ds_swizzle(__float_as_int(x), (2  << 10) | 0x1f));
    x += __int_as_float(__builtin_amdgcn_ds_swizzle(__float_as_int(x), (4  << 10) | 0x1f));
    x += __int_as_float(__builtin_amdgcn_ds_swizzle(__float_as_int(x), (8  << 10) | 0x1f));
    x += __int_as_float(__builtin_amdgcn_ds_swizzle(__float_as_int(x), (16 << 10) | 0x1f));
    return x;
}
__device__ __forceinline__ float swz_max(float x) {
    x = fmaxf(x, __int_as_float(__builtin_amdgcn_ds_swizzle(__float_as_int(x), (1  << 10) | 0x1f)));
    x = fmaxf(x, __int_as_float(__builtin_amdgcn_ds_swizzle(__float_as_int(x), (2  << 10) | 0x1f)));
    x = fmaxf(x, __int_as_float(__builtin_amdgcn_ds_swizzle(__float_as_int(x), (4  << 10) | 0x1f)));
    x = fmaxf(x, __int_as_float(__builtin_amdgcn_ds_swizzle(__float_as_int(x), (8  << 10) | 0x1f)));
    x = fmaxf(x, __int_as_float(__builtin_amdgcn_ds_swizzle(__float_as_int(x), (16 << 10) | 0x1f)));
    return x;
}

// Two rows per wave: lanes 0-31 -> row 2r, lanes 32-63 -> row 2r+1.
// Each lane holds 16 elements. Michelot from tau0 = max-1 (valid lower
// bound since p_max <= 1); sets nested & shrinking, exact finite
// convergence when both halves' support counts stabilize.
__global__ __launch_bounds__(BLOCK) void sparsemax_kernel(
    const float* __restrict__ x, float* __restrict__ out, int batch) {
    const int wv   = threadIdx.x >> 6;
    const int lane = threadIdx.x & 63;
    const int half = lane >> 5;          // which row of the pair
    const int l    = lane & 31;          // lane within 32-group
    const int row  = (blockIdx.x * WPB + wv) * 2 + half;
    if (row >= batch) return;

    const f32x4* xr = reinterpret_cast<const f32x4*>(x) + (size_t)row * (DIM / 4);
    f32x4 v0 = xr[l];
    f32x4 v1 = xr[l + 32];
    f32x4 v2 = xr[l + 64];
    f32x4 v3 = xr[l + 96];
    float z[16] = {v0.x, v0.y, v0.z, v0.w, v1.x, v1.y, v1.z, v1.w,
                   v2.x, v2.y, v2.z, v2.w, v3.x, v3.y, v3.z, v3.w};

    // --- tau0 = rowmax - 1 ---
    float m = z[0];
#pragma unroll
    for (int j = 1; j < 16; ++j) m = fmaxf(m, z[j]);
    m = swz_max(m);
    float tau = m - 1.0f;

    // --- Michelot: tau' = (S-1)/K over {z > tau}; K per half from the
    //     64-wide ballot (scalar pipe), S via 5-stage swizzle allreduce. ---
    int kp0 = -1, kp1 = -1;
    for (int it = 0; it < 32; ++it) {
        float S = 0.f;
        int K0 = 0, K1 = 0;
#pragma unroll
        for (int j = 0; j < 16; ++j) {
            const bool in = z[j] > tau;
            const unsigned long long b = __ballot(in);
            K0 += __popc((unsigned)b);
            K1 += __popc((unsigned)(b >> 32));
            S += in ? z[j] : 0.f;
        }
        S = swz_add(S);
        if (K0 == kp0 && K1 == kp1) break;   // both sets stable -> fixed point
        kp0 = K0; kp1 = K1;
        const float K = (float)(half ? K1 : K0);   // this half's support size
        tau = (S - 1.0f) * __builtin_amdgcn_rcpf(K);  // K >= 1 (max in set)
    }

    // --- epilogue: out = max(0, z - tau), nontemporal (write-once data;
    //     keeps input resident in L3) ---
    f32x4 o[4];
#pragma unroll
    for (int j = 0; j < 16; ++j) o[j >> 2][j & 3] = fmaxf(0.f, z[j] - tau);
    f32x4* orow = reinterpret_cast<f32x4*>(out) + (size_t)row * (DIM / 4);
    __builtin_nontemporal_store(o[0], orow + l);
    __builtin_nontemporal_store(o[1], orow + l + 32);
    __builtin_nontemporal_store(o[2], orow + l + 64);
    __builtin_nontemporal_store(o[3], orow + l + 96);
}

extern "C" void kernel_launch(void* const* d_in, const int* in_sizes, int n_in,
                              void* d_out, int out_size, void* d_ws, size_t ws_size,
                              hipStream_t stream) {
    const float* x = (const float*)d_in[0];
    float* out     = (float*)d_out;
    const int batch = in_sizes[0] / DIM;  // 65536
    const int grid  = (batch + ROWS_PER_BLOCK - 1) / ROWS_PER_BLOCK;
    sparsemax_kernel<<<grid, BLOCK, 0, stream>>>(x, out, batch);
}

// Round 4
// 229.528 us; speedup vs baseline: 1.0043x; 1.0043x over previous
//
#include <hip/hip_runtime.h>

typedef float f32x4 __attribute__((ext_vector_type(4)));

#define DIM 512
#define WPB 4                 // waves per block
#define BLOCK (64 * WPB)      // 256 threads
#define ROWS_PER_BLOCK (WPB * 2)

// DPP cross-lane move (VALU pipe, no LDS, ~4 cyc vs ~120 for ds ops).
// CTRL: 0xB1 = quad_perm[1,0,3,2] (xor1), 0x4E = quad_perm[2,3,0,1] (xor2),
// 0x141 = row_half_mirror (combines 4-groups in 8), 0x140 = row_mirror
// (combines 8-groups in 16). bound_ctrl=1: OOB reads 0 (never hit here).
template <int CTRL>
__device__ __forceinline__ float dpp_mov(float x) {
    return __int_as_float(
        __builtin_amdgcn_update_dpp(0, __float_as_int(x), CTRL, 0xF, 0xF, true));
}

// Allreduce within each 32-lane half: 4 DPP stages (VALU) + 1 ds_swizzle
// xor16 (BitMode stays inside the 32-group). Result identical in all 32 lanes.
__device__ __forceinline__ float red32_add(float x) {
    x += dpp_mov<0xB1>(x);
    x += dpp_mov<0x4E>(x);
    x += dpp_mov<0x141>(x);
    x += dpp_mov<0x140>(x);
    x += __int_as_float(__builtin_amdgcn_ds_swizzle(__float_as_int(x), (16 << 10) | 0x1f));
    return x;
}
__device__ __forceinline__ float red32_max(float x) {
    x = fmaxf(x, dpp_mov<0xB1>(x));
    x = fmaxf(x, dpp_mov<0x4E>(x));
    x = fmaxf(x, dpp_mov<0x141>(x));
    x = fmaxf(x, dpp_mov<0x140>(x));
    x = fmaxf(x, __int_as_float(__builtin_amdgcn_ds_swizzle(__float_as_int(x), (16 << 10) | 0x1f)));
    return x;
}

// Two rows per wave: lanes 0-31 -> row 2r, lanes 32-63 -> row 2r+1.
// Each lane holds 16 elements. Michelot from tau0 = max-1 (valid lower
// bound since p_max <= 1); support sets nested & shrinking -> exact finite
// convergence when both halves' counts stabilize.
__global__ __launch_bounds__(BLOCK) void sparsemax_kernel(
    const float* __restrict__ x, float* __restrict__ out, int batch) {
    const int wv   = threadIdx.x >> 6;
    const int lane = threadIdx.x & 63;
    const int half = lane >> 5;
    const int l    = lane & 31;
    const int row  = (blockIdx.x * WPB + wv) * 2 + half;
    if (row >= batch) return;

    const f32x4* xr = reinterpret_cast<const f32x4*>(x) + (size_t)row * (DIM / 4);
    f32x4 v0 = xr[l];
    f32x4 v1 = xr[l + 32];
    f32x4 v2 = xr[l + 64];
    f32x4 v3 = xr[l + 96];
    float z[16] = {v0.x, v0.y, v0.z, v0.w, v1.x, v1.y, v1.z, v1.w,
                   v2.x, v2.y, v2.z, v2.w, v3.x, v3.y, v3.z, v3.w};

    // --- tau0 = rowmax - 1 ---
    float m = z[0];
#pragma unroll
    for (int j = 1; j < 16; ++j) m = fmaxf(m, z[j]);
    m = red32_max(m);
    float tau = m - 1.0f;

    // --- Michelot: tau' = (S-1)/K over {z > tau}; K per half from 64-wide
    //     ballots (scalar pipe), S via DPP allreduce. ---
    int kp0 = -1, kp1 = -1;
    for (int it = 0; it < 32; ++it) {
        float S = 0.f;
        int K0 = 0, K1 = 0;
#pragma unroll
        for (int j = 0; j < 16; ++j) {
            const bool in = z[j] > tau;
            const unsigned long long b = __ballot(in);
            K0 += __popc((unsigned)b);
            K1 += __popc((unsigned)(b >> 32));
            S += in ? z[j] : 0.f;
        }
        S = red32_add(S);
        if (K0 == kp0 && K1 == kp1) break;   // both sets stable -> fixed point
        kp0 = K0; kp1 = K1;
        const float K = (float)(half ? K1 : K0);
        tau = (S - 1.0f) * __builtin_amdgcn_rcpf(K);   // K >= 1 (max in set)
    }

    // --- epilogue: out = max(0, z - tau), nontemporal (write-once) ---
    f32x4 o[4];
#pragma unroll
    for (int j = 0; j < 16; ++j) o[j >> 2][j & 3] = fmaxf(0.f, z[j] - tau);
    f32x4* orow = reinterpret_cast<f32x4*>(out) + (size_t)row * (DIM / 4);
    __builtin_nontemporal_store(o[0], orow + l);
    __builtin_nontemporal_store(o[1], orow + l + 32);
    __builtin_nontemporal_store(o[2], orow + l + 64);
    __builtin_nontemporal_store(o[3], orow + l + 96);
}

extern "C" void kernel_launch(void* const* d_in, const int* in_sizes, int n_in,
                              void* d_out, int out_size, void* d_ws, size_t ws_size,
                              hipStream_t stream) {
    const float* x = (const float*)d_in[0];
    float* out     = (float*)d_out;
    const int batch = in_sizes[0] / DIM;  // 65536
    const int grid  = (batch + ROWS_PER_BLOCK - 1) / ROWS_PER_BLOCK;
    sparsemax_kernel<<<grid, BLOCK, 0, stream>>>(x, out, batch);
}